// Round 1
// baseline (2557.773 us; speedup 1.0000x reference)
//
#include <hip/hip_runtime.h>
#include <hip/hip_bf16.h>

#define B_ 64
#define N_ 4096
#define D_ 256
#define S_ 8
#define NH_ 8
#define DK_ 32
#define ITERS_ 3
#define MLPH_ 512
#define EPS_ 1e-5f
#define M_ (B_*N_)          // 262144 rows of x

typedef unsigned short u16;
typedef short bf16x8 __attribute__((ext_vector_type(8)));
typedef float f32x4 __attribute__((ext_vector_type(4)));

__device__ __forceinline__ u16 f2bf(float f){
  unsigned int x = __float_as_uint(f);
  return (u16)((x + 0x7fffu + ((x >> 16) & 1u)) >> 16);   // RNE
}
__device__ __forceinline__ void unpack2(unsigned int u, float& lo, float& hi){
  lo = __uint_as_float(u << 16);
  hi = __uint_as_float(u & 0xffff0000u);
}

// ---------------------------------------------------------------- prep
// wkvT[n][k] = bf16( [wk|wv]^T ), w_ihT[d][j] = w_ih[j][d], w_hhT likewise
__global__ void prep_kernel(const float* __restrict__ wk, const float* __restrict__ wv,
                            const float* __restrict__ wih, const float* __restrict__ whh,
                            u16* __restrict__ wkvT, float* __restrict__ wihT,
                            float* __restrict__ whhT){
  int idx = blockIdx.x * 256 + threadIdx.x;
  if(idx < 512*256){
    int n = idx >> 8, k = idx & 255;
    float v = (n < 256) ? wk[k*256 + n] : wv[k*256 + (n-256)];
    wkvT[n*256 + k] = f2bf(v);
    return;
  }
  int i2 = idx - 512*256;
  if(i2 < 196608){           // w_ihT
    int d = i2 / 768, j = i2 - d*768;
    wihT[i2] = wih[j*256 + d];
    return;
  }
  int i3 = i2 - 196608;
  if(i3 < 196608){           // w_hhT
    int d = i3 / 768, j = i3 - d*768;
    whhT[i3] = whh[j*256 + d];
  }
}

// ---------------------------------------------------------------- slot init
__global__ void init_slots(const float* __restrict__ mu, const float* __restrict__ lsig,
                           const float* __restrict__ noise, float* __restrict__ slots){
  int idx = blockIdx.x * 256 + threadIdx.x;   // < 131072
  int d = idx & 255;
  slots[idx] = mu[d] + __expf(lsig[d]) * noise[idx];
}

// ---------------------------------------------------------------- LN(inputs) -> bf16
// one row (256) per wave; 4 waves/block
__global__ __launch_bounds__(256) void ln_kernel(const float* __restrict__ inp,
                                                 const float* __restrict__ g,
                                                 const float* __restrict__ b,
                                                 u16* __restrict__ xb){
  int wave = threadIdx.x >> 6, lane = threadIdx.x & 63;
  int row = blockIdx.x * 4 + wave;
  float4 v = *(const float4*)(inp + (size_t)row*D_ + lane*4);
  float s  = v.x+v.y+v.z+v.w;
  float ss = v.x*v.x + v.y*v.y + v.z*v.z + v.w*v.w;
  #pragma unroll
  for(int o=32;o>=1;o>>=1){ s += __shfl_xor(s,o,64); ss += __shfl_xor(ss,o,64); }
  float mean = s * (1.f/D_);
  float var  = ss * (1.f/D_) - mean*mean;
  float rstd = rsqrtf(var + EPS_);
  float4 gg = *(const float4*)(g + lane*4);
  float4 bb = *(const float4*)(b + lane*4);
  ushort4 o4;
  o4.x = f2bf((v.x-mean)*rstd*gg.x + bb.x);
  o4.y = f2bf((v.y-mean)*rstd*gg.y + bb.y);
  o4.z = f2bf((v.z-mean)*rstd*gg.z + bb.z);
  o4.w = f2bf((v.w-mean)*rstd*gg.w + bb.w);
  *(ushort4*)(xb + (size_t)row*D_ + lane*4) = o4;
}

// ---------------------------------------------------------------- K/V projection GEMM
// [M,256]bf16 @ [256,512]bf16 -> K,V bf16 [B,H,N,DK].  BM=128 BN=256 BK=64, 8 waves.
__global__ __launch_bounds__(512) void kv_gemm(const u16* __restrict__ xb,
                                               const u16* __restrict__ wkvT,
                                               const float* __restrict__ bk,
                                               const float* __restrict__ bv,
                                               u16* __restrict__ Kp, u16* __restrict__ Vp){
  __shared__ u16 As[128*72];   // stride 72 (pad 8) keeps 16B align, breaks bank aliasing
  __shared__ u16 Bs[256*72];   // B stored n-major (transposed), k contiguous
  int rt = blockIdx.x, ct = blockIdx.y;
  int tid = threadIdx.x;
  int w = tid >> 6, lane = tid & 63;
  int wm = w >> 2, wn = w & 3;           // 2x4 waves of 64x64
  int lr = lane & 15, quad = lane >> 4;
  f32x4 zf = {0.f,0.f,0.f,0.f};
  f32x4 acc[4][4];
  #pragma unroll
  for(int mt=0;mt<4;mt++)
    #pragma unroll
    for(int nt=0;nt<4;nt++) acc[mt][nt] = zf;

  for(int kk=0; kk<4; kk++){
    __syncthreads();
    #pragma unroll
    for(int p=0;p<2;p++){                  // A: 128x64 bf16
      int idx = tid + p*512;
      int r = idx >> 3, c8 = (idx & 7) * 8;
      uint4 t = *(const uint4*)(xb + (size_t)(rt*128 + r)*256 + kk*64 + c8);
      *(uint4*)(As + r*72 + c8) = t;
    }
    #pragma unroll
    for(int p=0;p<4;p++){                  // B^T: 256x64 bf16
      int idx = tid + p*512;
      int nr = idx >> 3, c8 = (idx & 7) * 8;
      uint4 t = *(const uint4*)(wkvT + (size_t)(ct*256 + nr)*256 + kk*64 + c8);
      *(uint4*)(Bs + nr*72 + c8) = t;
    }
    __syncthreads();
    #pragma unroll
    for(int k32=0;k32<64;k32+=32){
      bf16x8 a[4], b[4];
      #pragma unroll
      for(int mt=0;mt<4;mt++)
        a[mt] = *(const bf16x8*)(As + (wm*64 + mt*16 + lr)*72 + k32 + quad*8);
      #pragma unroll
      for(int nt=0;nt<4;nt++)
        b[nt] = *(const bf16x8*)(Bs + (wn*64 + nt*16 + lr)*72 + k32 + quad*8);
      #pragma unroll
      for(int mt=0;mt<4;mt++)
        #pragma unroll
        for(int nt=0;nt<4;nt++)
          acc[mt][nt] = __builtin_amdgcn_mfma_f32_16x16x32_bf16(a[mt], b[nt], acc[mt][nt], 0,0,0);
    }
  }
  // epilogue: C[row=quad*4+i][col=lr]  (m89-verified layout)
  #pragma unroll
  for(int mt=0;mt<4;mt++){
    #pragma unroll
    for(int nt=0;nt<4;nt++){
      int gc = ct*256 + wn*64 + nt*16 + lr;
      int gr0 = rt*128 + wm*64 + mt*16 + quad*4;
      #pragma unroll
      for(int i=0;i<4;i++){
        int gr = gr0 + i;
        int bb = gr >> 12, n = gr & 4095;
        float v = acc[mt][nt][i];
        if(gc < 256){
          int h = gc >> 5, d = gc & 31;
          Kp[((size_t)(bb*8 + h)*4096 + n)*32 + d] = f2bf(v + bk[gc]);
        } else {
          int c2 = gc - 256;
          int h = c2 >> 5, d = c2 & 31;
          Vp[((size_t)(bb*8 + h)*4096 + n)*32 + d] = f2bf(v + bv[c2]);
        }
      }
    }
  }
}

// ---------------------------------------------------------------- LN(slots)+Q proj
// one (b,s) row per block; Q written [B,H,S,DK]
__global__ __launch_bounds__(256) void qproj(const float* __restrict__ slots,
                                             const float* __restrict__ g,
                                             const float* __restrict__ b,
                                             const float* __restrict__ wq,
                                             const float* __restrict__ bq,
                                             float* __restrict__ Q){
  __shared__ float sp[256];
  __shared__ float red[8];
  int r = blockIdx.x, t = threadIdx.x;
  float v = slots[r*256 + t];
  float s1 = v, s2 = v*v;
  #pragma unroll
  for(int o=32;o>=1;o>>=1){ s1 += __shfl_xor(s1,o,64); s2 += __shfl_xor(s2,o,64); }
  int wv_ = t >> 6, lane = t & 63;
  if(lane==0){ red[wv_] = s1; red[4+wv_] = s2; }
  __syncthreads();
  float fs1 = red[0]+red[1]+red[2]+red[3];
  float fs2 = red[4]+red[5]+red[6]+red[7];
  float mean = fs1*(1.f/256.f);
  float var  = fs2*(1.f/256.f) - mean*mean;
  float rstd = rsqrtf(var + EPS_);
  sp[t] = (v - mean)*rstd*g[t] + b[t];
  __syncthreads();
  float acc = bq[t];
  for(int d=0; d<256; d++) acc = fmaf(sp[d], wq[d*256 + t], acc);
  int b_ = r >> 3, s_ = r & 7;
  int h = t >> 5, d_ = t & 31;
  Q[((b_*8 + h)*8 + s_)*32 + d_] = acc;
}

// ---------------------------------------------------------------- attention
// block = (b,h); wave = slot s; lane owns n = lane+64*i. Scores in 64 VGPRs.
__global__ __launch_bounds__(512) void attn(const float* __restrict__ Qw,
                                            const u16* __restrict__ Kp,
                                            const u16* __restrict__ Vp,
                                            float* __restrict__ Ow){
  const int bh = blockIdx.x;
  const int s = threadIdx.x >> 6, lane = threadIdx.x & 63;
  const float scale = 0.17677669529663687f;   // 1/sqrt(32)
  float q[32];
  {
    const float4* qp = (const float4*)(Qw + (bh*8 + s)*32);
    #pragma unroll
    for(int c=0;c<8;c++){
      float4 v = qp[c];
      q[c*4+0]=v.x; q[c*4+1]=v.y; q[c*4+2]=v.z; q[c*4+3]=v.w;
    }
  }
  const u16* kb = Kp + (size_t)bh*N_*DK_;
  float sc[64];
  #pragma unroll
  for(int i=0;i<64;i++){
    const uint4* kr = (const uint4*)(kb + (lane + i*64)*DK_);
    float acc = 0.f;
    #pragma unroll
    for(int c=0;c<4;c++){
      uint4 u = kr[c];
      float f0,f1,f2,f3,f4,f5,f6,f7;
      unpack2(u.x,f0,f1); unpack2(u.y,f2,f3); unpack2(u.z,f4,f5); unpack2(u.w,f6,f7);
      acc = fmaf(f0,q[c*8+0],acc); acc = fmaf(f1,q[c*8+1],acc);
      acc = fmaf(f2,q[c*8+2],acc); acc = fmaf(f3,q[c*8+3],acc);
      acc = fmaf(f4,q[c*8+4],acc); acc = fmaf(f5,q[c*8+5],acc);
      acc = fmaf(f6,q[c*8+6],acc); acc = fmaf(f7,q[c*8+7],acc);
    }
    sc[i] = acc * scale;
  }
  float mx = sc[0];
  #pragma unroll
  for(int i=1;i<64;i++) mx = fmaxf(mx, sc[i]);
  #pragma unroll
  for(int o=32;o>=1;o>>=1) mx = fmaxf(mx, __shfl_xor(mx,o,64));
  float l = 0.f;
  #pragma unroll
  for(int i=0;i<64;i++){ sc[i] = __expf(sc[i] - mx); l += sc[i]; }
  #pragma unroll
  for(int o=32;o>=1;o>>=1) l += __shfl_xor(l,o,64);
  float oacc[32] = {};
  const u16* vb = Vp + (size_t)bh*N_*DK_;
  #pragma unroll
  for(int i=0;i<64;i++){
    const uint4* vr = (const uint4*)(vb + (lane + i*64)*DK_);
    float p = sc[i];
    #pragma unroll
    for(int c=0;c<4;c++){
      uint4 u = vr[c];
      float f0,f1,f2,f3,f4,f5,f6,f7;
      unpack2(u.x,f0,f1); unpack2(u.y,f2,f3); unpack2(u.z,f4,f5); unpack2(u.w,f6,f7);
      oacc[c*8+0] = fmaf(p,f0,oacc[c*8+0]); oacc[c*8+1] = fmaf(p,f1,oacc[c*8+1]);
      oacc[c*8+2] = fmaf(p,f2,oacc[c*8+2]); oacc[c*8+3] = fmaf(p,f3,oacc[c*8+3]);
      oacc[c*8+4] = fmaf(p,f4,oacc[c*8+4]); oacc[c*8+5] = fmaf(p,f5,oacc[c*8+5]);
      oacc[c*8+6] = fmaf(p,f6,oacc[c*8+6]); oacc[c*8+7] = fmaf(p,f7,oacc[c*8+7]);
    }
  }
  #pragma unroll
  for(int d=0;d<32;d++){
    float x = oacc[d];
    #pragma unroll
    for(int o=32;o>=1;o>>=1) x += __shfl_xor(x,o,64);
    oacc[d] = x;
  }
  if(lane == 0){
    float inv = 1.f / l;
    float* op = Ow + (bh*8 + s)*32;
    #pragma unroll
    for(int d=0;d<32;d++) op[d] = oacc[d] * inv;
  }
}

// ---------------------------------------------------------------- out-proj + GRU + LN + MLP
// 4 rows per block so every weight value feeds 4 FMAs
__global__ __launch_bounds__(256) void gru_mlp(const float* __restrict__ Ain,
    const float* __restrict__ slots_in,
    const float* __restrict__ wo,  const float* __restrict__ bo,
    const float* __restrict__ wihT,const float* __restrict__ bih,
    const float* __restrict__ whhT,const float* __restrict__ bhh,
    const float* __restrict__ w1,  const float* __restrict__ b1,
    const float* __restrict__ w2,  const float* __restrict__ b2,
    const float* __restrict__ gm,  const float* __restrict__ bm,
    float* __restrict__ slots_out){
  __shared__ float xr[4][256], hr[4][256], o2[4][256], hnew[4][256], hid[4][512];
  __shared__ float red[4][8];
  int t = threadIdx.x, r0 = blockIdx.x*4;
  int wv_ = t >> 6, lane = t & 63;
  #pragma unroll
  for(int rr=0;rr<4;rr++){
    int r = r0+rr, b_ = r>>3, s_ = r&7;
    int h = t>>5, d = t&31;
    xr[rr][t] = Ain[((b_*8 + h)*8 + s_)*32 + d];   // un-transpose heads
    hr[rr][t] = slots_in[r*256 + t];
  }
  __syncthreads();
  { // out2 = xr @ wo + bo
    float a0=0,a1=0,a2=0,a3=0;
    for(int d=0; d<256; d++){
      float w = wo[d*256 + t];
      a0 = fmaf(xr[0][d],w,a0); a1 = fmaf(xr[1][d],w,a1);
      a2 = fmaf(xr[2][d],w,a2); a3 = fmaf(xr[3][d],w,a3);
    }
    float bv = bo[t];
    o2[0][t]=a0+bv; o2[1][t]=a1+bv; o2[2][t]=a2+bv; o2[3][t]=a3+bv;
  }
  __syncthreads();
  { // GRU gates (thread t owns column t of all 3 gate slices)
    float ir[4]={}, iz[4]={}, inn[4]={}, hrr[4]={}, hz[4]={}, hn[4]={};
    for(int d=0; d<256; d++){
      float wi0 = wihT[d*768 + t], wi1 = wihT[d*768 + 256 + t], wi2 = wihT[d*768 + 512 + t];
      float wh0 = whhT[d*768 + t], wh1 = whhT[d*768 + 256 + t], wh2 = whhT[d*768 + 512 + t];
      #pragma unroll
      for(int rr=0;rr<4;rr++){
        float xo = o2[rr][d], hh = hr[rr][d];
        ir[rr]  = fmaf(xo,wi0,ir[rr]);  iz[rr] = fmaf(xo,wi1,iz[rr]);  inn[rr] = fmaf(xo,wi2,inn[rr]);
        hrr[rr] = fmaf(hh,wh0,hrr[rr]); hz[rr] = fmaf(hh,wh1,hz[rr]);  hn[rr]  = fmaf(hh,wh2,hn[rr]);
      }
    }
    float bi0 = bih[t], bi1 = bih[256+t], bi2 = bih[512+t];
    float bh0 = bhh[t], bh1 = bhh[256+t], bh2 = bhh[512+t];
    #pragma unroll
    for(int rr=0;rr<4;rr++){
      float rg = 1.f/(1.f + __expf(-(ir[rr]+bi0 + hrr[rr]+bh0)));
      float zg = 1.f/(1.f + __expf(-(iz[rr]+bi1 + hz[rr]+bh1)));
      float ng = tanhf(inn[rr]+bi2 + rg*(hn[rr]+bh2));
      hnew[rr][t] = (1.f - zg)*ng + zg*hr[rr][t];
    }
  }
  __syncthreads();
  // LN(hnew) per row -> m stored in xr (xr is dead)
  #pragma unroll
  for(int rr=0;rr<4;rr++){
    float v = hnew[rr][t];
    float s1=v, s2=v*v;
    #pragma unroll
    for(int o=32;o>=1;o>>=1){ s1 += __shfl_xor(s1,o,64); s2 += __shfl_xor(s2,o,64); }
    if(lane==0){ red[rr][wv_]=s1; red[rr][4+wv_]=s2; }
  }
  __syncthreads();
  {
    float gmt = gm[t], bmt = bm[t];
    #pragma unroll
    for(int rr=0;rr<4;rr++){
      float fs1 = red[rr][0]+red[rr][1]+red[rr][2]+red[rr][3];
      float fs2 = red[rr][4]+red[rr][5]+red[rr][6]+red[rr][7];
      float mean = fs1*(1.f/256.f);
      float var  = fs2*(1.f/256.f) - mean*mean;
      float rstd = rsqrtf(var + EPS_);
      xr[rr][t] = (hnew[rr][t]-mean)*rstd*gmt + bmt;
    }
  }
  __syncthreads();
  { // hid = relu(m @ w1 + b1), thread t -> cols t, t+256
    float c0[4]={}, c1[4]={};
    for(int d=0; d<256; d++){
      float wA = w1[d*512 + t], wB = w1[d*512 + 256 + t];
      #pragma unroll
      for(int rr=0;rr<4;rr++){ float mv = xr[rr][d]; c0[rr]=fmaf(mv,wA,c0[rr]); c1[rr]=fmaf(mv,wB,c1[rr]); }
    }
    float b1a = b1[t], b1b = b1[256+t];
    #pragma unroll
    for(int rr=0;rr<4;rr++){
      hid[rr][t]     = fmaxf(c0[rr]+b1a, 0.f);
      hid[rr][t+256] = fmaxf(c1[rr]+b1b, 0.f);
    }
  }
  __syncthreads();
  { // slots_out = hnew + hid @ w2 + b2
    float a[4]={};
    for(int k=0;k<512;k++){
      float w = w2[k*256 + t];
      #pragma unroll
      for(int rr=0;rr<4;rr++) a[rr] = fmaf(hid[rr][k], w, a[rr]);
    }
    float b2t = b2[t];
    #pragma unroll
    for(int rr=0;rr<4;rr++){
      int r = r0+rr;
      slots_out[r*256 + t] = hnew[rr][t] + a[rr] + b2t;
    }
  }
}

// ----------------------------------------------------------------
extern "C" void kernel_launch(void* const* d_in, const int* in_sizes, int n_in,
                              void* d_out, int out_size, void* d_ws, size_t ws_size,
                              hipStream_t stream){
  const float* inputs = (const float*)d_in[0];
  const float* noise  = (const float*)d_in[1];
  const float* mu     = (const float*)d_in[2];
  const float* lsig   = (const float*)d_in[3];
  const float* wq  = (const float*)d_in[4];  const float* bq  = (const float*)d_in[5];
  const float* wk  = (const float*)d_in[6];  const float* bk  = (const float*)d_in[7];
  const float* wv  = (const float*)d_in[8];  const float* bv  = (const float*)d_in[9];
  const float* wo  = (const float*)d_in[10]; const float* bo  = (const float*)d_in[11];
  const float* wih = (const float*)d_in[12]; const float* bih = (const float*)d_in[13];
  const float* whh = (const float*)d_in[14]; const float* bhh = (const float*)d_in[15];
  const float* w1  = (const float*)d_in[16]; const float* b1  = (const float*)d_in[17];
  const float* w2  = (const float*)d_in[18]; const float* b2  = (const float*)d_in[19];
  const float* g_in= (const float*)d_in[20]; const float* b_in= (const float*)d_in[21];
  const float* g_sl= (const float*)d_in[22]; const float* b_sl= (const float*)d_in[23];
  const float* g_ml= (const float*)d_in[24]; const float* b_ml= (const float*)d_in[25];

  const size_t sz_big = (size_t)M_ * D_ * 2;   // 134,217,728 B each
  size_t need = 3*sz_big + 512*256*2 + 2*(256*768*4) + 3*(512*256*4);
  if(ws_size < need) return;   // workspace too small: fail loudly (wrong answer) instead of OOB

  char* p = (char*)d_ws;
  u16*   xb   = (u16*)p;   p += sz_big;
  u16*   Kp   = (u16*)p;   p += sz_big;
  u16*   Vp   = (u16*)p;   p += sz_big;
  u16*   wkvT = (u16*)p;   p += 512*256*2;
  float* wihT = (float*)p; p += 256*768*4;
  float* whhT = (float*)p; p += 256*768*4;
  float* slots= (float*)p; p += 512*256*4;
  float* Qw   = (float*)p; p += 512*256*4;
  float* Ow   = (float*)p; p += 512*256*4;

  prep_kernel<<<2048, 256, 0, stream>>>(wk, wv, wih, whh, wkvT, wihT, whhT);
  init_slots <<<512, 256, 0, stream>>>(mu, lsig, noise, slots);
  ln_kernel  <<<M_/4, 256, 0, stream>>>(inputs, g_in, b_in, xb);
  kv_gemm    <<<dim3(M_/128, 2), 512, 0, stream>>>(xb, wkvT, bk, bv, Kp, Vp);

  for(int it = 0; it < ITERS_; ++it){
    qproj<<<512, 256, 0, stream>>>(slots, g_sl, b_sl, wq, bq, Qw);
    attn <<<512, 512, 0, stream>>>(Qw, Kp, Vp, Ow);
    float* outp = (it == ITERS_-1) ? (float*)d_out : slots;
    gru_mlp<<<128, 256, 0, stream>>>(Ow, slots, wo, bo, wihT, bih, whhT, bhh,
                                     w1, b1, w2, b2, g_ml, b_ml, outp);
  }
}

// Round 4
// 1412.577 us; speedup vs baseline: 1.8107x; 1.8107x over previous
//
#include <hip/hip_runtime.h>
#include <hip/hip_bf16.h>

#define B_ 64
#define N_ 4096
#define D_ 256
#define S_ 8
#define NH_ 8
#define DK_ 32
#define ITERS_ 3
#define MLPH_ 512
#define EPS_ 1e-5f
#define M_ (B_*N_)          // 262144 rows of x
#define NEG_BIG_ -3.0e38f   // finite sentinel: exp(NEG_BIG_-x) underflows to 0.f

typedef unsigned short u16;
typedef short bf16x8 __attribute__((ext_vector_type(8)));
typedef float f32x4 __attribute__((ext_vector_type(4)));

__device__ __forceinline__ u16 f2bf(float f){
  unsigned int x = __float_as_uint(f);
  return (u16)((x + 0x7fffu + ((x >> 16) & 1u)) >> 16);   // RNE
}
__device__ __forceinline__ void unpack2(unsigned int u, float& lo, float& hi){
  lo = __uint_as_float(u << 16);
  hi = __uint_as_float(u & 0xffff0000u);
}

// ---------------------------------------------------------------- prep
// wkvT[n][k] = bf16( [wk|wv]^T ), w_ihT[d][j] = w_ih[j][d], w_hhT likewise
__global__ void prep_kernel(const float* __restrict__ wk, const float* __restrict__ wv,
                            const float* __restrict__ wih, const float* __restrict__ whh,
                            u16* __restrict__ wkvT, float* __restrict__ wihT,
                            float* __restrict__ whhT){
  int idx = blockIdx.x * 256 + threadIdx.x;
  if(idx < 512*256){
    int n = idx >> 8, k = idx & 255;
    float v = (n < 256) ? wk[k*256 + n] : wv[k*256 + (n-256)];
    wkvT[n*256 + k] = f2bf(v);
    return;
  }
  int i2 = idx - 512*256;
  if(i2 < 196608){           // w_ihT
    int d = i2 / 768, j = i2 - d*768;
    wihT[i2] = wih[j*256 + d];
    return;
  }
  int i3 = i2 - 196608;
  if(i3 < 196608){           // w_hhT
    int d = i3 / 768, j = i3 - d*768;
    whhT[i3] = whh[j*256 + d];
  }
}

// ---------------------------------------------------------------- slot init
__global__ void init_slots(const float* __restrict__ mu, const float* __restrict__ lsig,
                           const float* __restrict__ noise, float* __restrict__ slots){
  int idx = blockIdx.x * 256 + threadIdx.x;   // < 131072
  int d = idx & 255;
  slots[idx] = mu[d] + __expf(lsig[d]) * noise[idx];
}

// ---------------------------------------------------------------- LN(inputs) -> bf16
// one row (256) per wave; 4 waves/block
__global__ __launch_bounds__(256) void ln_kernel(const float* __restrict__ inp,
                                                 const float* __restrict__ g,
                                                 const float* __restrict__ b,
                                                 u16* __restrict__ xb){
  int wave = threadIdx.x >> 6, lane = threadIdx.x & 63;
  int row = blockIdx.x * 4 + wave;
  float4 v = *(const float4*)(inp + (size_t)row*D_ + lane*4);
  float s  = v.x+v.y+v.z+v.w;
  float ss = v.x*v.x + v.y*v.y + v.z*v.z + v.w*v.w;
  #pragma unroll
  for(int o=32;o>=1;o>>=1){ s += __shfl_xor(s,o,64); ss += __shfl_xor(ss,o,64); }
  float mean = s * (1.f/D_);
  float var  = ss * (1.f/D_) - mean*mean;
  float rstd = rsqrtf(var + EPS_);
  float4 gg = *(const float4*)(g + lane*4);
  float4 bb = *(const float4*)(b + lane*4);
  ushort4 o4;
  o4.x = f2bf((v.x-mean)*rstd*gg.x + bb.x);
  o4.y = f2bf((v.y-mean)*rstd*gg.y + bb.y);
  o4.z = f2bf((v.z-mean)*rstd*gg.z + bb.z);
  o4.w = f2bf((v.w-mean)*rstd*gg.w + bb.w);
  *(ushort4*)(xb + (size_t)row*D_ + lane*4) = o4;
}

// ---------------------------------------------------------------- K/V projection GEMM
// [M,256]bf16 @ [256,512]bf16 -> K,V bf16 [B,H,N,DK].  BM=128 BN=256 BK=64, 8 waves.
__global__ __launch_bounds__(512) void kv_gemm(const u16* __restrict__ xb,
                                               const u16* __restrict__ wkvT,
                                               const float* __restrict__ bk,
                                               const float* __restrict__ bv,
                                               u16* __restrict__ Kp, u16* __restrict__ Vp){
  __shared__ u16 As[128*72];   // stride 72 (pad 8) keeps 16B align, breaks bank aliasing
  __shared__ u16 Bs[256*72];   // B stored n-major (transposed), k contiguous
  int rt = blockIdx.x, ct = blockIdx.y;
  int tid = threadIdx.x;
  int w = tid >> 6, lane = tid & 63;
  int wm = w >> 2, wn = w & 3;           // 2x4 waves of 64x64
  int lr = lane & 15, quad = lane >> 4;
  f32x4 zf = {0.f,0.f,0.f,0.f};
  f32x4 acc[4][4];
  #pragma unroll
  for(int mt=0;mt<4;mt++)
    #pragma unroll
    for(int nt=0;nt<4;nt++) acc[mt][nt] = zf;

  for(int kk=0; kk<4; kk++){
    __syncthreads();
    #pragma unroll
    for(int p=0;p<2;p++){                  // A: 128x64 bf16
      int idx = tid + p*512;
      int r = idx >> 3, c8 = (idx & 7) * 8;
      uint4 t = *(const uint4*)(xb + (size_t)(rt*128 + r)*256 + kk*64 + c8);
      *(uint4*)(As + r*72 + c8) = t;
    }
    #pragma unroll
    for(int p=0;p<4;p++){                  // B^T: 256x64 bf16
      int idx = tid + p*512;
      int nr = idx >> 3, c8 = (idx & 7) * 8;
      uint4 t = *(const uint4*)(wkvT + (size_t)(ct*256 + nr)*256 + kk*64 + c8);
      *(uint4*)(Bs + nr*72 + c8) = t;
    }
    __syncthreads();
    #pragma unroll
    for(int k32=0;k32<64;k32+=32){
      bf16x8 a[4], b[4];
      #pragma unroll
      for(int mt=0;mt<4;mt++)
        a[mt] = *(const bf16x8*)(As + (wm*64 + mt*16 + lr)*72 + k32 + quad*8);
      #pragma unroll
      for(int nt=0;nt<4;nt++)
        b[nt] = *(const bf16x8*)(Bs + (wn*64 + nt*16 + lr)*72 + k32 + quad*8);
      #pragma unroll
      for(int mt=0;mt<4;mt++)
        #pragma unroll
        for(int nt=0;nt<4;nt++)
          acc[mt][nt] = __builtin_amdgcn_mfma_f32_16x16x32_bf16(a[mt], b[nt], acc[mt][nt], 0,0,0);
    }
  }
  // epilogue: C[row=quad*4+i][col=lr]  (m89-verified layout)
  #pragma unroll
  for(int mt=0;mt<4;mt++){
    #pragma unroll
    for(int nt=0;nt<4;nt++){
      int gc = ct*256 + wn*64 + nt*16 + lr;
      int gr0 = rt*128 + wm*64 + mt*16 + quad*4;
      #pragma unroll
      for(int i=0;i<4;i++){
        int gr = gr0 + i;
        int bb = gr >> 12, n = gr & 4095;
        float v = acc[mt][nt][i];
        if(gc < 256){
          int h = gc >> 5, d = gc & 31;
          Kp[((size_t)(bb*8 + h)*4096 + n)*32 + d] = f2bf(v + bk[gc]);
        } else {
          int c2 = gc - 256;
          int h = c2 >> 5, d = c2 & 31;
          Vp[((size_t)(bb*8 + h)*4096 + n)*32 + d] = f2bf(v + bv[c2]);
        }
      }
    }
  }
}

// ---------------------------------------------------------------- LN(slots)+Q proj
// one (b,s) row per block; Q written [B,H,S,DK]
__global__ __launch_bounds__(256) void qproj(const float* __restrict__ slots,
                                             const float* __restrict__ g,
                                             const float* __restrict__ b,
                                             const float* __restrict__ wq,
                                             const float* __restrict__ bq,
                                             float* __restrict__ Q){
  __shared__ float sp[256];
  __shared__ float red[8];
  int r = blockIdx.x, t = threadIdx.x;
  float v = slots[r*256 + t];
  float s1 = v, s2 = v*v;
  #pragma unroll
  for(int o=32;o>=1;o>>=1){ s1 += __shfl_xor(s1,o,64); s2 += __shfl_xor(s2,o,64); }
  int wv_ = t >> 6, lane = t & 63;
  if(lane==0){ red[wv_] = s1; red[4+wv_] = s2; }
  __syncthreads();
  float fs1 = red[0]+red[1]+red[2]+red[3];
  float fs2 = red[4]+red[5]+red[6]+red[7];
  float mean = fs1*(1.f/256.f);
  float var  = fs2*(1.f/256.f) - mean*mean;
  float rstd = rsqrtf(var + EPS_);
  sp[t] = (v - mean)*rstd*g[t] + b[t];
  __syncthreads();
  float acc = bq[t];
  for(int d=0; d<256; d++) acc = fmaf(sp[d], wq[d*256 + t], acc);
  int b_ = r >> 3, s_ = r & 7;
  int h = t >> 5, d_ = t & 31;
  Q[((b_*8 + h)*8 + s_)*32 + d_] = acc;
}

// ---------------------------------------------------------------- attention (online softmax, no spill)
// block = (b,h); wave = slot s; lane owns rows n = lane + 64*i. Chunks of 4 rows,
// deferred rescale: one oacc*corr per chunk. Live state/lane: q[32], oacc[32], m, l.
__global__ __launch_bounds__(512) void attn(const float* __restrict__ Qw,
                                            const u16* __restrict__ Kp,
                                            const u16* __restrict__ Vp,
                                            float* __restrict__ Ow){
  const int bh = blockIdx.x;
  const int s = threadIdx.x >> 6, lane = threadIdx.x & 63;
  const float scale = 0.17677669529663687f;   // 1/sqrt(32)
  float q[32];
  {
    const float4* qp = (const float4*)(Qw + (bh*8 + s)*32);
    #pragma unroll
    for(int c=0;c<8;c++){
      float4 v = qp[c];
      q[c*4+0]=v.x; q[c*4+1]=v.y; q[c*4+2]=v.z; q[c*4+3]=v.w;
    }
  }
  const u16* kb = Kp + (size_t)bh*N_*DK_;
  const u16* vb = Vp + (size_t)bh*N_*DK_;
  float m = NEG_BIG_, l = 0.f;
  float oacc[32];
  #pragma unroll
  for(int d=0;d<32;d++) oacc[d] = 0.f;

  #pragma unroll 1
  for(int ch=0; ch<16; ch++){
    // ---- scores for 4 rows
    float sc[4];
    #pragma unroll
    for(int j=0;j<4;j++){
      const uint4* kr = (const uint4*)(kb + (size_t)(lane + (ch*4+j)*64)*DK_);
      float acc = 0.f;
      #pragma unroll
      for(int c=0;c<4;c++){
        uint4 u = kr[c];
        float f0,f1,f2,f3,f4,f5,f6,f7;
        unpack2(u.x,f0,f1); unpack2(u.y,f2,f3); unpack2(u.z,f4,f5); unpack2(u.w,f6,f7);
        acc = fmaf(f0,q[c*8+0],acc); acc = fmaf(f1,q[c*8+1],acc);
        acc = fmaf(f2,q[c*8+2],acc); acc = fmaf(f3,q[c*8+3],acc);
        acc = fmaf(f4,q[c*8+4],acc); acc = fmaf(f5,q[c*8+5],acc);
        acc = fmaf(f6,q[c*8+6],acc); acc = fmaf(f7,q[c*8+7],acc);
      }
      sc[j] = acc * scale;
    }
    // ---- online-softmax update (deferred rescale, once per chunk)
    float cmax = fmaxf(fmaxf(sc[0],sc[1]), fmaxf(sc[2],sc[3]));
    float newm = fmaxf(m, cmax);
    float corr = __expf(m - newm);           // underflows to 0 on first chunk
    m = newm;
    float p[4];
    float psum = 0.f;
    #pragma unroll
    for(int j=0;j<4;j++){ p[j] = __expf(sc[j] - newm); psum += p[j]; }
    l = l * corr + psum;
    #pragma unroll
    for(int d=0;d<32;d++) oacc[d] *= corr;
    // ---- PV accumulate for the 4 rows
    #pragma unroll
    for(int j=0;j<4;j++){
      const uint4* vr = (const uint4*)(vb + (size_t)(lane + (ch*4+j)*64)*DK_);
      float pj = p[j];
      #pragma unroll
      for(int c=0;c<4;c++){
        uint4 u = vr[c];
        float f0,f1,f2,f3,f4,f5,f6,f7;
        unpack2(u.x,f0,f1); unpack2(u.y,f2,f3); unpack2(u.z,f4,f5); unpack2(u.w,f6,f7);
        oacc[c*8+0] = fmaf(pj,f0,oacc[c*8+0]); oacc[c*8+1] = fmaf(pj,f1,oacc[c*8+1]);
        oacc[c*8+2] = fmaf(pj,f2,oacc[c*8+2]); oacc[c*8+3] = fmaf(pj,f3,oacc[c*8+3]);
        oacc[c*8+4] = fmaf(pj,f4,oacc[c*8+4]); oacc[c*8+5] = fmaf(pj,f5,oacc[c*8+5]);
        oacc[c*8+6] = fmaf(pj,f6,oacc[c*8+6]); oacc[c*8+7] = fmaf(pj,f7,oacc[c*8+7]);
      }
    }
  }
  // ---- cross-lane merge of (m, l, oacc) via xor butterfly
  #pragma unroll
  for(int o=32;o>=1;o>>=1){
    float m2 = __shfl_xor(m, o, 64);
    float l2 = __shfl_xor(l, o, 64);
    float nm = fmaxf(m, m2);
    float a = __expf(m - nm), b = __expf(m2 - nm);
    l = l*a + l2*b;
    #pragma unroll
    for(int d=0;d<32;d++){
      float o2 = __shfl_xor(oacc[d], o, 64);
      oacc[d] = oacc[d]*a + o2*b;
    }
    m = nm;
  }
  if(lane == 0){
    float inv = 1.f / l;
    float* op = Ow + (bh*8 + s)*32;
    #pragma unroll
    for(int d=0;d<32;d++) op[d] = oacc[d] * inv;
  }
}

// ---------------------------------------------------------------- out-proj + GRU + LN + MLP
// 4 rows per block so every weight value feeds 4 FMAs
__global__ __launch_bounds__(256) void gru_mlp(const float* __restrict__ Ain,
    const float* __restrict__ slots_in,
    const float* __restrict__ wo,  const float* __restrict__ bo,
    const float* __restrict__ wihT,const float* __restrict__ bih,
    const float* __restrict__ whhT,const float* __restrict__ bhh,
    const float* __restrict__ w1,  const float* __restrict__ b1,
    const float* __restrict__ w2,  const float* __restrict__ b2,
    const float* __restrict__ gm,  const float* __restrict__ bm,
    float* __restrict__ slots_out){
  __shared__ float xr[4][256], hr[4][256], o2[4][256], hnew[4][256], hid[4][512];
  __shared__ float red[4][8];
  int t = threadIdx.x, r0 = blockIdx.x*4;
  int wv_ = t >> 6, lane = t & 63;
  #pragma unroll
  for(int rr=0;rr<4;rr++){
    int r = r0+rr, b_ = r>>3, s_ = r&7;
    int h = t>>5, d = t&31;
    xr[rr][t] = Ain[((b_*8 + h)*8 + s_)*32 + d];   // un-transpose heads
    hr[rr][t] = slots_in[r*256 + t];
  }
  __syncthreads();
  { // out2 = xr @ wo + bo
    float a0=0,a1=0,a2=0,a3=0;
    for(int d=0; d<256; d++){
      float w = wo[d*256 + t];
      a0 = fmaf(xr[0][d],w,a0); a1 = fmaf(xr[1][d],w,a1);
      a2 = fmaf(xr[2][d],w,a2); a3 = fmaf(xr[3][d],w,a3);
    }
    float bv = bo[t];
    o2[0][t]=a0+bv; o2[1][t]=a1+bv; o2[2][t]=a2+bv; o2[3][t]=a3+bv;
  }
  __syncthreads();
  { // GRU gates (thread t owns column t of all 3 gate slices)
    float ir[4]={}, iz[4]={}, inn[4]={}, hrr[4]={}, hz[4]={}, hn[4]={};
    for(int d=0; d<256; d++){
      float wi0 = wihT[d*768 + t], wi1 = wihT[d*768 + 256 + t], wi2 = wihT[d*768 + 512 + t];
      float wh0 = whhT[d*768 + t], wh1 = whhT[d*768 + 256 + t], wh2 = whhT[d*768 + 512 + t];
      #pragma unroll
      for(int rr=0;rr<4;rr++){
        float xo = o2[rr][d], hh = hr[rr][d];
        ir[rr]  = fmaf(xo,wi0,ir[rr]);  iz[rr] = fmaf(xo,wi1,iz[rr]);  inn[rr] = fmaf(xo,wi2,inn[rr]);
        hrr[rr] = fmaf(hh,wh0,hrr[rr]); hz[rr] = fmaf(hh,wh1,hz[rr]);  hn[rr]  = fmaf(hh,wh2,hn[rr]);
      }
    }
    float bi0 = bih[t], bi1 = bih[256+t], bi2 = bih[512+t];
    float bh0 = bhh[t], bh1 = bhh[256+t], bh2 = bhh[512+t];
    #pragma unroll
    for(int rr=0;rr<4;rr++){
      float rg = 1.f/(1.f + __expf(-(ir[rr]+bi0 + hrr[rr]+bh0)));
      float zg = 1.f/(1.f + __expf(-(iz[rr]+bi1 + hz[rr]+bh1)));
      float ng = tanhf(inn[rr]+bi2 + rg*(hn[rr]+bh2));
      hnew[rr][t] = (1.f - zg)*ng + zg*hr[rr][t];
    }
  }
  __syncthreads();
  // LN(hnew) per row -> m stored in xr (xr is dead)
  #pragma unroll
  for(int rr=0;rr<4;rr++){
    float v = hnew[rr][t];
    float s1=v, s2=v*v;
    #pragma unroll
    for(int o=32;o>=1;o>>=1){ s1 += __shfl_xor(s1,o,64); s2 += __shfl_xor(s2,o,64); }
    if(lane==0){ red[rr][wv_]=s1; red[rr][4+wv_]=s2; }
  }
  __syncthreads();
  {
    float gmt = gm[t], bmt = bm[t];
    #pragma unroll
    for(int rr=0;rr<4;rr++){
      float fs1 = red[rr][0]+red[rr][1]+red[rr][2]+red[rr][3];
      float fs2 = red[rr][4]+red[rr][5]+red[rr][6]+red[rr][7];
      float mean = fs1*(1.f/256.f);
      float var  = fs2*(1.f/256.f) - mean*mean;
      float rstd = rsqrtf(var + EPS_);
      xr[rr][t] = (hnew[rr][t]-mean)*rstd*gmt + bmt;
    }
  }
  __syncthreads();
  { // hid = relu(m @ w1 + b1), thread t -> cols t, t+256
    float c0[4]={}, c1[4]={};
    for(int d=0; d<256; d++){
      float wA = w1[d*512 + t], wB = w1[d*512 + 256 + t];
      #pragma unroll
      for(int rr=0;rr<4;rr++){ float mv = xr[rr][d]; c0[rr]=fmaf(mv,wA,c0[rr]); c1[rr]=fmaf(mv,wB,c1[rr]); }
    }
    float b1a = b1[t], b1b = b1[256+t];
    #pragma unroll
    for(int rr=0;rr<4;rr++){
      hid[rr][t]     = fmaxf(c0[rr]+b1a, 0.f);
      hid[rr][t+256] = fmaxf(c1[rr]+b1b, 0.f);
    }
  }
  __syncthreads();
  { // slots_out = hnew + hid @ w2 + b2
    float a[4]={};
    for(int k=0;k<512;k++){
      float w = w2[k*256 + t];
      #pragma unroll
      for(int rr=0;rr<4;rr++) a[rr] = fmaf(hid[rr][k], w, a[rr]);
    }
    float b2t = b2[t];
    #pragma unroll
    for(int rr=0;rr<4;rr++){
      int r = r0+rr;
      slots_out[r*256 + t] = hnew[rr][t] + a[rr] + b2t;
    }
  }
}

// ----------------------------------------------------------------
extern "C" void kernel_launch(void* const* d_in, const int* in_sizes, int n_in,
                              void* d_out, int out_size, void* d_ws, size_t ws_size,
                              hipStream_t stream){
  const float* inputs = (const float*)d_in[0];
  const float* noise  = (const float*)d_in[1];
  const float* mu     = (const float*)d_in[2];
  const float* lsig   = (const float*)d_in[3];
  const float* wq  = (const float*)d_in[4];  const float* bq  = (const float*)d_in[5];
  const float* wk  = (const float*)d_in[6];  const float* bk  = (const float*)d_in[7];
  const float* wv  = (const float*)d_in[8];  const float* bv  = (const float*)d_in[9];
  const float* wo  = (const float*)d_in[10]; const float* bo  = (const float*)d_in[11];
  const float* wih = (const float*)d_in[12]; const float* bih = (const float*)d_in[13];
  const float* whh = (const float*)d_in[14]; const float* bhh = (const float*)d_in[15];
  const float* w1  = (const float*)d_in[16]; const float* b1  = (const float*)d_in[17];
  const float* w2  = (const float*)d_in[18]; const float* b2  = (const float*)d_in[19];
  const float* g_in= (const float*)d_in[20]; const float* b_in= (const float*)d_in[21];
  const float* g_sl= (const float*)d_in[22]; const float* b_sl= (const float*)d_in[23];
  const float* g_ml= (const float*)d_in[24]; const float* b_ml= (const float*)d_in[25];

  const size_t sz_big = (size_t)M_ * D_ * 2;   // 134,217,728 B each
  size_t need = 3*sz_big + 512*256*2 + 2*(256*768*4) + 3*(512*256*4);
  if(ws_size < need) return;   // workspace too small: fail loudly (wrong answer) instead of OOB

  char* p = (char*)d_ws;
  u16*   xb   = (u16*)p;   p += sz_big;
  u16*   Kp   = (u16*)p;   p += sz_big;
  u16*   Vp   = (u16*)p;   p += sz_big;
  u16*   wkvT = (u16*)p;   p += 512*256*2;
  float* wihT = (float*)p; p += 256*768*4;
  float* whhT = (float*)p; p += 256*768*4;
  float* slots= (float*)p; p += 512*256*4;
  float* Qw   = (float*)p; p += 512*256*4;
  float* Ow   = (float*)p; p += 512*256*4;

  prep_kernel<<<2048, 256, 0, stream>>>(wk, wv, wih, whh, wkvT, wihT, whhT);
  init_slots <<<512, 256, 0, stream>>>(mu, lsig, noise, slots);
  ln_kernel  <<<M_/4, 256, 0, stream>>>(inputs, g_in, b_in, xb);
  kv_gemm    <<<dim3(M_/128, 2), 512, 0, stream>>>(xb, wkvT, bk, bv, Kp, Vp);

  for(int it = 0; it < ITERS_; ++it){
    qproj<<<512, 256, 0, stream>>>(slots, g_sl, b_sl, wq, bq, Qw);
    attn <<<512, 512, 0, stream>>>(Qw, Kp, Vp, Ow);
    float* outp = (it == ITERS_-1) ? (float*)d_out : slots;
    gru_mlp<<<128, 256, 0, stream>>>(Ow, slots, wo, bo, wihT, bih, whhT, bhh,
                                     w1, b1, w2, b2, g_ml, b_ml, outp);
  }
}

// Round 6
// 1411.551 us; speedup vs baseline: 1.8120x; 1.0007x over previous
//
#include <hip/hip_runtime.h>
#include <hip/hip_bf16.h>

#define B_ 64
#define N_ 4096
#define D_ 256
#define S_ 8
#define NH_ 8
#define DK_ 32
#define ITERS_ 3
#define MLPH_ 512
#define EPS_ 1e-5f
#define M_ (B_*N_)          // 262144 rows of x
#define NEG_BIG_ -3.0e38f   // finite sentinel: exp(NEG_BIG_-x) underflows to 0.f
#define NSPLIT_ 4           // attention N-partitions per (b,h)

typedef unsigned short u16;
typedef short bf16x8 __attribute__((ext_vector_type(8)));
typedef float f32x4 __attribute__((ext_vector_type(4)));

__device__ __forceinline__ u16 f2bf(float f){
  unsigned int x = __float_as_uint(f);
  return (u16)((x + 0x7fffu + ((x >> 16) & 1u)) >> 16);   // RNE
}
__device__ __forceinline__ void unpack2(unsigned int u, float& lo, float& hi){
  lo = __uint_as_float(u << 16);
  hi = __uint_as_float(u & 0xffff0000u);
}

// ---------------------------------------------------------------- prep
__global__ void prep_kernel(const float* __restrict__ wk, const float* __restrict__ wv,
                            const float* __restrict__ wih, const float* __restrict__ whh,
                            u16* __restrict__ wkvT, float* __restrict__ wihT,
                            float* __restrict__ whhT){
  int idx = blockIdx.x * 256 + threadIdx.x;
  if(idx < 512*256){
    int n = idx >> 8, k = idx & 255;
    float v = (n < 256) ? wk[k*256 + n] : wv[k*256 + (n-256)];
    wkvT[n*256 + k] = f2bf(v);
    return;
  }
  int i2 = idx - 512*256;
  if(i2 < 196608){           // w_ihT
    int d = i2 / 768, j = i2 - d*768;
    wihT[i2] = wih[j*256 + d];
    return;
  }
  int i3 = i2 - 196608;
  if(i3 < 196608){           // w_hhT
    int d = i3 / 768, j = i3 - d*768;
    whhT[i3] = whh[j*256 + d];
  }
}

// ---------------------------------------------------------------- slot init
__global__ void init_slots(const float* __restrict__ mu, const float* __restrict__ lsig,
                           const float* __restrict__ noise, float* __restrict__ slots){
  int idx = blockIdx.x * 256 + threadIdx.x;   // < 131072
  int d = idx & 255;
  slots[idx] = mu[d] + __expf(lsig[d]) * noise[idx];
}

// ---------------------------------------------------------------- LN(inputs) -> bf16
__global__ __launch_bounds__(256) void ln_kernel(const float* __restrict__ inp,
                                                 const float* __restrict__ g,
                                                 const float* __restrict__ b,
                                                 u16* __restrict__ xb){
  int wave = threadIdx.x >> 6, lane = threadIdx.x & 63;
  int row = blockIdx.x * 4 + wave;
  float4 v = *(const float4*)(inp + (size_t)row*D_ + lane*4);
  float s  = v.x+v.y+v.z+v.w;
  float ss = v.x*v.x + v.y*v.y + v.z*v.z + v.w*v.w;
  #pragma unroll
  for(int o=32;o>=1;o>>=1){ s += __shfl_xor(s,o,64); ss += __shfl_xor(ss,o,64); }
  float mean = s * (1.f/D_);
  float var  = ss * (1.f/D_) - mean*mean;
  float rstd = rsqrtf(var + EPS_);
  float4 gg = *(const float4*)(g + lane*4);
  float4 bb = *(const float4*)(b + lane*4);
  ushort4 o4;
  o4.x = f2bf((v.x-mean)*rstd*gg.x + bb.x);
  o4.y = f2bf((v.y-mean)*rstd*gg.y + bb.y);
  o4.z = f2bf((v.z-mean)*rstd*gg.z + bb.z);
  o4.w = f2bf((v.w-mean)*rstd*gg.w + bb.w);
  *(ushort4*)(xb + (size_t)row*D_ + lane*4) = o4;
}

// ---------------------------------------------------------------- K/V projection GEMM
__global__ __launch_bounds__(512) void kv_gemm(const u16* __restrict__ xb,
                                               const u16* __restrict__ wkvT,
                                               const float* __restrict__ bk,
                                               const float* __restrict__ bv,
                                               u16* __restrict__ Kp, u16* __restrict__ Vp){
  __shared__ u16 As[128*72];
  __shared__ u16 Bs[256*72];
  int rt = blockIdx.x, ct = blockIdx.y;
  int tid = threadIdx.x;
  int w = tid >> 6, lane = tid & 63;
  int wm = w >> 2, wn = w & 3;           // 2x4 waves of 64x64
  int lr = lane & 15, quad = lane >> 4;
  f32x4 zf = {0.f,0.f,0.f,0.f};
  f32x4 acc[4][4];
  #pragma unroll
  for(int mt=0;mt<4;mt++)
    #pragma unroll
    for(int nt=0;nt<4;nt++) acc[mt][nt] = zf;

  for(int kk=0; kk<4; kk++){
    __syncthreads();
    #pragma unroll
    for(int p=0;p<2;p++){                  // A: 128x64 bf16
      int idx = tid + p*512;
      int r = idx >> 3, c8 = (idx & 7) * 8;
      uint4 t = *(const uint4*)(xb + (size_t)(rt*128 + r)*256 + kk*64 + c8);
      *(uint4*)(As + r*72 + c8) = t;
    }
    #pragma unroll
    for(int p=0;p<4;p++){                  // B^T: 256x64 bf16
      int idx = tid + p*512;
      int nr = idx >> 3, c8 = (idx & 7) * 8;
      uint4 t = *(const uint4*)(wkvT + (size_t)(ct*256 + nr)*256 + kk*64 + c8);
      *(uint4*)(Bs + nr*72 + c8) = t;
    }
    __syncthreads();
    #pragma unroll
    for(int k32=0;k32<64;k32+=32){
      bf16x8 a[4], b[4];
      #pragma unroll
      for(int mt=0;mt<4;mt++)
        a[mt] = *(const bf16x8*)(As + (wm*64 + mt*16 + lr)*72 + k32 + quad*8);
      #pragma unroll
      for(int nt=0;nt<4;nt++)
        b[nt] = *(const bf16x8*)(Bs + (wn*64 + nt*16 + lr)*72 + k32 + quad*8);
      #pragma unroll
      for(int mt=0;mt<4;mt++)
        #pragma unroll
        for(int nt=0;nt<4;nt++)
          acc[mt][nt] = __builtin_amdgcn_mfma_f32_16x16x32_bf16(a[mt], b[nt], acc[mt][nt], 0,0,0);
    }
  }
  // epilogue: C[row=quad*4+i][col=lr]
  #pragma unroll
  for(int mt=0;mt<4;mt++){
    #pragma unroll
    for(int nt=0;nt<4;nt++){
      int gc = ct*256 + wn*64 + nt*16 + lr;
      int gr0 = rt*128 + wm*64 + mt*16 + quad*4;
      #pragma unroll
      for(int i=0;i<4;i++){
        int gr = gr0 + i;
        int bb = gr >> 12, n = gr & 4095;
        float v = acc[mt][nt][i];
        if(gc < 256){
          int h = gc >> 5, d = gc & 31;
          Kp[((size_t)(bb*8 + h)*4096 + n)*32 + d] = f2bf(v + bk[gc]);
        } else {
          int c2 = gc - 256;
          int h = c2 >> 5, d = c2 & 31;
          Vp[((size_t)(bb*8 + h)*4096 + n)*32 + d] = f2bf(v + bv[c2]);
        }
      }
    }
  }
}

// ---------------------------------------------------------------- LN(slots)+Q proj
__global__ __launch_bounds__(256) void qproj(const float* __restrict__ slots,
                                             const float* __restrict__ g,
                                             const float* __restrict__ b,
                                             const float* __restrict__ wq,
                                             const float* __restrict__ bq,
                                             float* __restrict__ Q){
  __shared__ float sp[256];
  __shared__ float red[8];
  int r = blockIdx.x, t = threadIdx.x;
  float v = slots[r*256 + t];
  float s1 = v, s2 = v*v;
  #pragma unroll
  for(int o=32;o>=1;o>>=1){ s1 += __shfl_xor(s1,o,64); s2 += __shfl_xor(s2,o,64); }
  int wv_ = t >> 6, lane = t & 63;
  if(lane==0){ red[wv_] = s1; red[4+wv_] = s2; }
  __syncthreads();
  float fs1 = red[0]+red[1]+red[2]+red[3];
  float fs2 = red[4]+red[5]+red[6]+red[7];
  float mean = fs1*(1.f/256.f);
  float var  = fs2*(1.f/256.f) - mean*mean;
  float rstd = rsqrtf(var + EPS_);
  sp[t] = (v - mean)*rstd*g[t] + b[t];
  __syncthreads();
  float acc = bq[t];
  for(int d=0; d<256; d++) acc = fmaf(sp[d], wq[d*256 + t], acc);
  int b_ = r >> 3, s_ = r & 7;
  int h = t >> 5, d_ = t & 31;
  Q[((b_*8 + h)*8 + s_)*32 + d_] = acc;
}

// ---------------------------------------------------------------- attention, N-split partials
// grid (512, NSPLIT_); block = (b,h); wave = slot s; split handles 1024 rows,
// lane owns 16 rows (4 chunks of 4). Writes per-split partials (m, l, oacc[32]).
__global__ __launch_bounds__(512) void attn_part(const float* __restrict__ Qw,
                                                 const u16* __restrict__ Kp,
                                                 const u16* __restrict__ Vp,
                                                 float2* __restrict__ Pml,
                                                 float* __restrict__ Po){
  const int bh = blockIdx.x, sp = blockIdx.y;
  const int s = threadIdx.x >> 6, lane = threadIdx.x & 63;
  const float scale = 0.17677669529663687f;   // 1/sqrt(32)
  float q[32];
  {
    const float4* qp = (const float4*)(Qw + (bh*8 + s)*32);
    #pragma unroll
    for(int c=0;c<8;c++){
      float4 v = qp[c];
      q[c*4+0]=v.x; q[c*4+1]=v.y; q[c*4+2]=v.z; q[c*4+3]=v.w;
    }
  }
  const int base = sp * (N_/NSPLIT_);          // 1024-row slice
  const u16* kb = Kp + (size_t)bh*N_*DK_ + (size_t)base*DK_;
  const u16* vb = Vp + (size_t)bh*N_*DK_ + (size_t)base*DK_;
  float m = NEG_BIG_, l = 0.f;
  float oacc[32];
  #pragma unroll
  for(int d=0;d<32;d++) oacc[d] = 0.f;

  #pragma unroll 1
  for(int ch=0; ch<4; ch++){
    // ---- scores for 4 rows
    float sc[4];
    #pragma unroll
    for(int j=0;j<4;j++){
      const uint4* kr = (const uint4*)(kb + (size_t)(lane + (ch*4+j)*64)*DK_);
      float acc = 0.f;
      #pragma unroll
      for(int c=0;c<4;c++){
        uint4 u = kr[c];
        float f0,f1,f2,f3,f4,f5,f6,f7;
        unpack2(u.x,f0,f1); unpack2(u.y,f2,f3); unpack2(u.z,f4,f5); unpack2(u.w,f6,f7);
        acc = fmaf(f0,q[c*8+0],acc); acc = fmaf(f1,q[c*8+1],acc);
        acc = fmaf(f2,q[c*8+2],acc); acc = fmaf(f3,q[c*8+3],acc);
        acc = fmaf(f4,q[c*8+4],acc); acc = fmaf(f5,q[c*8+5],acc);
        acc = fmaf(f6,q[c*8+6],acc); acc = fmaf(f7,q[c*8+7],acc);
      }
      sc[j] = acc * scale;
    }
    // ---- issue V loads now (addresses independent of softmax scalars)
    uint4 vreg[4][4];
    #pragma unroll
    for(int j=0;j<4;j++){
      const uint4* vr = (const uint4*)(vb + (size_t)(lane + (ch*4+j)*64)*DK_);
      #pragma unroll
      for(int c=0;c<4;c++) vreg[j][c] = vr[c];
    }
    // ---- online-softmax update (deferred rescale, once per chunk)
    float cmax = fmaxf(fmaxf(sc[0],sc[1]), fmaxf(sc[2],sc[3]));
    float newm = fmaxf(m, cmax);
    float corr = __expf(m - newm);
    m = newm;
    float p[4];
    float psum = 0.f;
    #pragma unroll
    for(int j=0;j<4;j++){ p[j] = __expf(sc[j] - newm); psum += p[j]; }
    l = l * corr + psum;
    #pragma unroll
    for(int d=0;d<32;d++) oacc[d] *= corr;
    // ---- PV accumulate from registers
    #pragma unroll
    for(int j=0;j<4;j++){
      float pj = p[j];
      #pragma unroll
      for(int c=0;c<4;c++){
        uint4 u = vreg[j][c];
        float f0,f1,f2,f3,f4,f5,f6,f7;
        unpack2(u.x,f0,f1); unpack2(u.y,f2,f3); unpack2(u.z,f4,f5); unpack2(u.w,f6,f7);
        oacc[c*8+0] = fmaf(pj,f0,oacc[c*8+0]); oacc[c*8+1] = fmaf(pj,f1,oacc[c*8+1]);
        oacc[c*8+2] = fmaf(pj,f2,oacc[c*8+2]); oacc[c*8+3] = fmaf(pj,f3,oacc[c*8+3]);
        oacc[c*8+4] = fmaf(pj,f4,oacc[c*8+4]); oacc[c*8+5] = fmaf(pj,f5,oacc[c*8+5]);
        oacc[c*8+6] = fmaf(pj,f6,oacc[c*8+6]); oacc[c*8+7] = fmaf(pj,f7,oacc[c*8+7]);
      }
    }
  }
  // ---- cross-lane merge of (m, l, oacc) via xor butterfly
  #pragma unroll
  for(int o=32;o>=1;o>>=1){
    float m2 = __shfl_xor(m, o, 64);
    float l2 = __shfl_xor(l, o, 64);
    float nm = fmaxf(m, m2);
    float a = __expf(m - nm), b = __expf(m2 - nm);
    l = l*a + l2*b;
    #pragma unroll
    for(int d=0;d<32;d++){
      float o2 = __shfl_xor(oacc[d], o, 64);
      oacc[d] = oacc[d]*a + o2*b;
    }
    m = nm;
  }
  if(lane == 0){
    int pi = (bh*8 + s)*NSPLIT_ + sp;
    Pml[pi] = make_float2(m, l);
    float* op = Po + (size_t)pi*32;
    #pragma unroll
    for(int d=0;d<32;d++) op[d] = oacc[d];   // unnormalized
  }
}

// ---------------------------------------------------------------- merge split partials -> Ow
// one thread per (row, d): row = (bh*8+s) in [0,4096), d in [0,32)
__global__ __launch_bounds__(256) void attn_merge(const float2* __restrict__ Pml,
                                                  const float* __restrict__ Po,
                                                  float* __restrict__ Ow){
  int gid = blockIdx.x * 256 + threadIdx.x;   // < 131072
  int row = gid >> 5, d = gid & 31;
  float2 ml[NSPLIT_];
  #pragma unroll
  for(int k=0;k<NSPLIT_;k++) ml[k] = Pml[row*NSPLIT_ + k];
  float M = ml[0].x;
  #pragma unroll
  for(int k=1;k<NSPLIT_;k++) M = fmaxf(M, ml[k].x);
  float L = 0.f, o = 0.f;
  #pragma unroll
  for(int k=0;k<NSPLIT_;k++){
    float e = __expf(ml[k].x - M);
    L += ml[k].y * e;
    o += Po[(size_t)(row*NSPLIT_ + k)*32 + d] * e;
  }
  Ow[row*32 + d] = o / L;
}

// ---------------------------------------------------------------- out-proj + GRU + LN + MLP
__global__ __launch_bounds__(256) void gru_mlp(const float* __restrict__ Ain,
    const float* __restrict__ slots_in,
    const float* __restrict__ wo,  const float* __restrict__ bo,
    const float* __restrict__ wihT,const float* __restrict__ bih,
    const float* __restrict__ whhT,const float* __restrict__ bhh,
    const float* __restrict__ w1,  const float* __restrict__ b1,
    const float* __restrict__ w2,  const float* __restrict__ b2,
    const float* __restrict__ gm,  const float* __restrict__ bm,
    float* __restrict__ slots_out){
  __shared__ float xr[4][256], hr[4][256], o2[4][256], hnew[4][256], hid[4][512];
  __shared__ float red[4][8];
  int t = threadIdx.x, r0 = blockIdx.x*4;
  int wv_ = t >> 6, lane = t & 63;
  #pragma unroll
  for(int rr=0;rr<4;rr++){
    int r = r0+rr, b_ = r>>3, s_ = r&7;
    int h = t>>5, d = t&31;
    xr[rr][t] = Ain[((b_*8 + h)*8 + s_)*32 + d];   // un-transpose heads
    hr[rr][t] = slots_in[r*256 + t];
  }
  __syncthreads();
  { // out2 = xr @ wo + bo
    float a0=0,a1=0,a2=0,a3=0;
    for(int d=0; d<256; d++){
      float w = wo[d*256 + t];
      a0 = fmaf(xr[0][d],w,a0); a1 = fmaf(xr[1][d],w,a1);
      a2 = fmaf(xr[2][d],w,a2); a3 = fmaf(xr[3][d],w,a3);
    }
    float bv = bo[t];
    o2[0][t]=a0+bv; o2[1][t]=a1+bv; o2[2][t]=a2+bv; o2[3][t]=a3+bv;
  }
  __syncthreads();
  { // GRU gates
    float ir[4]={}, iz[4]={}, inn[4]={}, hrr[4]={}, hz[4]={}, hn[4]={};
    for(int d=0; d<256; d++){
      float wi0 = wihT[d*768 + t], wi1 = wihT[d*768 + 256 + t], wi2 = wihT[d*768 + 512 + t];
      float wh0 = whhT[d*768 + t], wh1 = whhT[d*768 + 256 + t], wh2 = whhT[d*768 + 512 + t];
      #pragma unroll
      for(int rr=0;rr<4;rr++){
        float xo = o2[rr][d], hh = hr[rr][d];
        ir[rr]  = fmaf(xo,wi0,ir[rr]);  iz[rr] = fmaf(xo,wi1,iz[rr]);  inn[rr] = fmaf(xo,wi2,inn[rr]);
        hrr[rr] = fmaf(hh,wh0,hrr[rr]); hz[rr] = fmaf(hh,wh1,hz[rr]);  hn[rr]  = fmaf(hh,wh2,hn[rr]);
      }
    }
    float bi0 = bih[t], bi1 = bih[256+t], bi2 = bih[512+t];
    float bh0 = bhh[t], bh1 = bhh[256+t], bh2 = bhh[512+t];
    #pragma unroll
    for(int rr=0;rr<4;rr++){
      float rg = 1.f/(1.f + __expf(-(ir[rr]+bi0 + hrr[rr]+bh0)));
      float zg = 1.f/(1.f + __expf(-(iz[rr]+bi1 + hz[rr]+bh1)));
      float ng = tanhf(inn[rr]+bi2 + rg*(hn[rr]+bh2));
      hnew[rr][t] = (1.f - zg)*ng + zg*hr[rr][t];
    }
  }
  __syncthreads();
  // LN(hnew) per row -> m stored in xr (xr is dead)
  #pragma unroll
  for(int rr=0;rr<4;rr++){
    float v = hnew[rr][t];
    float s1=v, s2=v*v;
    #pragma unroll
    for(int o=32;o>=1;o>>=1){ s1 += __shfl_xor(s1,o,64); s2 += __shfl_xor(s2,o,64); }
    if(lane==0){ red[rr][wv_]=s1; red[rr][4+wv_]=s2; }
  }
  __syncthreads();
  {
    float gmt = gm[t], bmt = bm[t];
    #pragma unroll
    for(int rr=0;rr<4;rr++){
      float fs1 = red[rr][0]+red[rr][1]+red[rr][2]+red[rr][3];
      float fs2 = red[rr][4]+red[rr][5]+red[rr][6]+red[rr][7];
      float mean = fs1*(1.f/256.f);
      float var  = fs2*(1.f/256.f) - mean*mean;
      float rstd = rsqrtf(var + EPS_);
      xr[rr][t] = (hnew[rr][t]-mean)*rstd*gmt + bmt;
    }
  }
  __syncthreads();
  { // hid = relu(m @ w1 + b1)
    float c0[4]={}, c1[4]={};
    for(int d=0; d<256; d++){
      float wA = w1[d*512 + t], wB = w1[d*512 + 256 + t];
      #pragma unroll
      for(int rr=0;rr<4;rr++){ float mv = xr[rr][d]; c0[rr]=fmaf(mv,wA,c0[rr]); c1[rr]=fmaf(mv,wB,c1[rr]); }
    }
    float b1a = b1[t], b1b = b1[256+t];
    #pragma unroll
    for(int rr=0;rr<4;rr++){
      hid[rr][t]     = fmaxf(c0[rr]+b1a, 0.f);
      hid[rr][t+256] = fmaxf(c1[rr]+b1b, 0.f);
    }
  }
  __syncthreads();
  { // slots_out = hnew + hid @ w2 + b2
    float a[4]={};
    for(int k=0;k<512;k++){
      float w = w2[k*256 + t];
      #pragma unroll
      for(int rr=0;rr<4;rr++) a[rr] = fmaf(hid[rr][k], w, a[rr]);
    }
    float b2t = b2[t];
    #pragma unroll
    for(int rr=0;rr<4;rr++){
      int r = r0+rr;
      slots_out[r*256 + t] = hnew[rr][t] + a[rr] + b2t;
    }
  }
}

// ----------------------------------------------------------------
extern "C" void kernel_launch(void* const* d_in, const int* in_sizes, int n_in,
                              void* d_out, int out_size, void* d_ws, size_t ws_size,
                              hipStream_t stream){
  const float* inputs = (const float*)d_in[0];
  const float* noise  = (const float*)d_in[1];
  const float* mu     = (const float*)d_in[2];
  const float* lsig   = (const float*)d_in[3];
  const float* wq  = (const float*)d_in[4];  const float* bq  = (const float*)d_in[5];
  const float* wk  = (const float*)d_in[6];  const float* bk  = (const float*)d_in[7];
  const float* wv  = (const float*)d_in[8];  const float* bv  = (const float*)d_in[9];
  const float* wo  = (const float*)d_in[10]; const float* bo  = (const float*)d_in[11];
  const float* wih = (const float*)d_in[12]; const float* bih = (const float*)d_in[13];
  const float* whh = (const float*)d_in[14]; const float* bhh = (const float*)d_in[15];
  const float* w1  = (const float*)d_in[16]; const float* b1  = (const float*)d_in[17];
  const float* w2  = (const float*)d_in[18]; const float* b2  = (const float*)d_in[19];
  const float* g_in= (const float*)d_in[20]; const float* b_in= (const float*)d_in[21];
  const float* g_sl= (const float*)d_in[22]; const float* b_sl= (const float*)d_in[23];
  const float* g_ml= (const float*)d_in[24]; const float* b_ml= (const float*)d_in[25];

  const size_t sz_big = (size_t)M_ * D_ * 2;   // 134,217,728 B each
  size_t need = 3*sz_big + 512*256*2 + 2*(256*768*4) + 3*(512*256*4)
              + 4096*NSPLIT_*8 + (size_t)4096*NSPLIT_*32*4;
  if(ws_size < need) return;

  char* p = (char*)d_ws;
  u16*   xb   = (u16*)p;   p += sz_big;
  u16*   Kp   = (u16*)p;   p += sz_big;
  u16*   Vp   = (u16*)p;   p += sz_big;
  u16*   wkvT = (u16*)p;   p += 512*256*2;
  float* wihT = (float*)p; p += 256*768*4;
  float* whhT = (float*)p; p += 256*768*4;
  float* slots= (float*)p; p += 512*256*4;
  float* Qw   = (float*)p; p += 512*256*4;
  float* Ow   = (float*)p; p += 512*256*4;
  float2* Pml = (float2*)p; p += 4096*NSPLIT_*8;
  float* Po   = (float*)p;  p += (size_t)4096*NSPLIT_*32*4;

  prep_kernel<<<2048, 256, 0, stream>>>(wk, wv, wih, whh, wkvT, wihT, whhT);
  init_slots <<<512, 256, 0, stream>>>(mu, lsig, noise, slots);
  ln_kernel  <<<M_/4, 256, 0, stream>>>(inputs, g_in, b_in, xb);
  kv_gemm    <<<dim3(M_/128, 2), 512, 0, stream>>>(xb, wkvT, bk, bv, Kp, Vp);

  for(int it = 0; it < ITERS_; ++it){
    qproj<<<512, 256, 0, stream>>>(slots, g_sl, b_sl, wq, bq, Qw);
    attn_part<<<dim3(512, NSPLIT_), 512, 0, stream>>>(Qw, Kp, Vp, Pml, Po);
    attn_merge<<<512, 256, 0, stream>>>(Pml, Po, Ow);
    float* outp = (it == ITERS_-1) ? (float*)d_out : slots;
    gru_mlp<<<128, 256, 0, stream>>>(Ow, slots, wo, bo, wihT, bih, whhT, bhh,
                                     w1, b1, w2, b2, g_ml, b_ml, outp);
  }
}